// Round 8
// baseline (113.013 us; speedup 1.0000x reference)
//
#include <hip/hip_runtime.h>
#include <hip/hip_bf16.h>
#include <float.h>

// VQ-VAE quantization for x:[8,64,32,32,32] f32, embedding:[512,64] f32.
// Outputs (flat, f32): [0] loss, [1..16777216] quantized [B,C,D,H,W], [16777217] perplexity.

#define EDIM      64
#define NCODES    512
#define SPATIAL   32768        // 32*32*32
#define OUT_ELEMS 16777216     // 8*64*32768
#define NROWS     262144       // 8*32768

typedef __attribute__((ext_vector_type(8))) short  short8;
typedef __attribute__((ext_vector_type(4))) float  float4v;
typedef __attribute__((ext_vector_type(4))) int    int4v;
typedef __attribute__((ext_vector_type(4))) unsigned short ushort4v;

static __device__ __forceinline__ unsigned pack_bf16x2(float lo, float hi) {
    union { float f; unsigned u; } a, b; a.f = lo; b.f = hi;
    unsigned ra = (a.u + 0x7FFFu + ((a.u >> 16) & 1u)) >> 16;   // RNE
    unsigned rb = (b.u + 0x7FFFu + ((b.u >> 16) & 1u)) & 0xFFFF0000u;
    return ra | rb;
}

// ---------------- prep: bf16(-2*e) table, |e|^2 + 0.5 key bias, zero counts -
__global__ void vq_prep(const float* __restrict__ emb,
                        unsigned* __restrict__ counts,
                        float* __restrict__ eNormB,
                        short* __restrict__ ebf) {
    int j = blockIdx.x;        // 512 blocks
    int c = threadIdx.x;       // 64 threads = 1 wave
    float v = emb[j * EDIM + c];
    union { float f; unsigned u; } t; t.f = -2.0f * v;
    ebf[j * EDIM + c] = (short)((t.u + 0x7FFFu + ((t.u >> 16) & 1u)) >> 16);
    float sq = v * v;
    #pragma unroll
    for (int m = 32; m; m >>= 1) sq += __shfl_xor(sq, m, 64);
    if (c == 0) {
        eNormB[j] = sq + 0.5f;   // key = 0.5 + |e|^2 - 2x.e  (positive, ~0.5)
        counts[j] = 0u;
    }
}

// ---------------- xprep: x[C][S] -> row-major bf16 xbf[row][64]; sum x^2 ----
__global__ __launch_bounds__(256) void vq_xprep(const float* __restrict__ x,
                                                unsigned short* __restrict__ xbf,
                                                float* __restrict__ xpart) {
    __shared__ float red4[4];
    const int tid = threadIdx.x;
    const int blk = blockIdx.x;           // 1024 blocks
    const int b   = blk >> 7;
    const int s0  = (blk & 127) << 8;     // 256 rows per block, 1 per thread
    const float* xp = x + ((long)b << 21) + s0 + tid;

    unsigned row[32];                     // this thread's row, packed bf16 pairs
    float x2 = 0.0f;
    #pragma unroll
    for (int c = 0; c < 64; c += 2) {
        float v0 = xp[(long)c << 15];         // coalesced: lanes contiguous in s
        float v1 = xp[(long)(c + 1) << 15];
        x2 += v0 * v0 + v1 * v1;
        row[c >> 1] = pack_bf16x2(v0, v1);
    }
    int4v* dst = (int4v*)(xbf + ((long)(b * SPATIAL + s0 + tid) << 6));
    #pragma unroll
    for (int q = 0; q < 8; ++q) dst[q] = *(int4v*)&row[q * 4];

    #pragma unroll
    for (int m = 32; m; m >>= 1) x2 += __shfl_xor(x2, m, 64);
    if ((tid & 63) == 0) red4[tid >> 6] = x2;
    __syncthreads();
    if (tid == 0) xpart[blk] = red4[0] + red4[1] + red4[2] + red4[3];
}

// ---------------- argmin: 64 rows/block, waves split the CODE dimension -----
// 4096 blocks x 256 thr: wave w scans codes [w*128, w*128+128) for the same
// 64 rows -> per-wave serial path is 8 jt iterations (was 32), and the grid
// gives a 32-waves/CU occupancy ceiling. Cross-wave merge via LDS atomicMin.
__global__ __launch_bounds__(256) void vq_argmin(
        const unsigned short* __restrict__ xbf,
        const float* __restrict__ eNormB,
        const short* __restrict__ ebf,
        unsigned short* __restrict__ idx_out,
        float* __restrict__ dpart) {

    __shared__ unsigned kmin[64];

    const int tid  = threadIdx.x;              // 256 threads = 4 waves
    const int wave = tid >> 6;
    const int lane = tid & 63;
    const int lrow = lane & 15;    // A-row / B-col / D-col lane field
    const int lk   = lane >> 4;    // k-chunk / D-row-group lane field
    const int row0 = blockIdx.x << 6;          // 4096 blocks, 64 rows/block

    if (tid < 64) kmin[tid] = 0xFFFFFFFFu;

    // ---- A fragments: 4 row-tiles x 2 k-chunks (same rows for all 4 waves;
    //      wave 1-3's reads hit L1 behind wave 0) ----------------------------
    short8 afr[4][2];
    #pragma unroll
    for (int r = 0; r < 4; ++r) {
        const long rbase = (long)(row0 + r * 16 + lrow) << 6;
        afr[r][0] = *(const short8*)(xbf + rbase + lk * 8);
        afr[r][1] = *(const short8*)(xbf + rbase + 32 + lk * 8);
    }
    __syncthreads();   // kmin init visible before any atomicMin

    // ---- scan this wave's 128 codes; key = bits(0.5+|e|^2-2x.e) low9 <- j --
    unsigned key[4][4];
    #pragma unroll
    for (int r = 0; r < 4; ++r)
        #pragma unroll
        for (int q = 0; q < 4; ++q) key[r][q] = 0xFFFFFFFFu;

    const short8* ebv = (const short8*)ebf;
    const int jbase = wave << 7;               // 128 codes per wave
    #pragma unroll
    for (int jt = 0; jt < 8; ++jt) {
        const int j = jbase + jt * 16 + lrow;         // this lane's code (B col)
        short8 b0 = ebv[j * 8 + lk];                  // channels [lk*8 .. +7]
        short8 b1 = ebv[j * 8 + 4 + lk];              // channels [32+lk*8 .. +7]
        float  en = eNormB[j];
        float4v cinit = {en, en, en, en};
        #pragma unroll
        for (int r = 0; r < 4; ++r) {
            float4v acc = cinit;
            acc = __builtin_amdgcn_mfma_f32_16x16x32_bf16(afr[r][0], b0, acc, 0, 0, 0);
            acc = __builtin_amdgcn_mfma_f32_16x16x32_bf16(afr[r][1], b1, acc, 0, 0, 0);
            #pragma unroll
            for (int q = 0; q < 4; ++q) {
                unsigned u = (__float_as_uint(acc[q]) & 0xFFFFFE00u) | (unsigned)j;
                key[r][q] = min(key[r][q], u);
            }
        }
    }

    // ---- min butterfly across the 16 code-lanes ----------------------------
    #pragma unroll
    for (int r = 0; r < 4; ++r)
        #pragma unroll
        for (int q = 0; q < 4; ++q) {
            unsigned k = key[r][q];
            #pragma unroll
            for (int m = 1; m < 16; m <<= 1)
                k = min(k, (unsigned)__shfl_xor((int)k, m, 64));
            key[r][q] = k;
        }

    // ---- cross-wave merge: LDS atomicMin over the 64 rows ------------------
    if (lrow == 0) {
        #pragma unroll
        for (int r = 0; r < 4; ++r)
            #pragma unroll
            for (int q = 0; q < 4; ++q)
                atomicMin(&kmin[r * 16 + lk * 4 + q], key[r][q]);
    }
    __syncthreads();

    // ---- wave 0: write idx (64 ushorts), reduce distance partial -----------
    if (tid < 64) {
        unsigned k = kmin[tid];
        idx_out[row0 + tid] = (unsigned short)(k & 511u);
        float d = __uint_as_float(k & 0xFFFFFE00u) - 0.5f;
        #pragma unroll
        for (int m = 32; m; m >>= 1) d += __shfl_xor(d, m, 64);
        if (tid == 0) dpart[blockIdx.x] = d;
    }
}

// ---------------- histogram: LDS bins, few global atomics -------------------
__global__ __launch_bounds__(256) void vq_hist(const unsigned short* __restrict__ idx,
                                               unsigned* __restrict__ counts) {
    __shared__ unsigned h[NCODES];
    const int tid = threadIdx.x;
    h[tid] = 0u; h[tid + 256] = 0u;
    __syncthreads();
    const unsigned* p = (const unsigned*)idx;          // 2 ushorts per load
    for (int i = blockIdx.x * 256 + tid; i < NROWS / 2; i += 64 * 256) {
        unsigned v = p[i];
        atomicAdd(&h[v & 0xFFFFu], 1u);
        atomicAdd(&h[v >> 16], 1u);
    }
    __syncthreads();
    atomicAdd(&counts[tid], h[tid]);
    atomicAdd(&counts[tid + 256], h[tid + 256]);
}

// ---------------- scatter: exact f32 codebook rows -> [C][S] output ---------
__global__ __launch_bounds__(256) void vq_scatter(const float* __restrict__ emb,
                                                  const unsigned short* __restrict__ idx,
                                                  float* __restrict__ out) {
    const int tid = threadIdx.x;
    const int blk = blockIdx.x;             // 1024 blocks
    const int b   = blk >> 7;
    const int s0  = (blk & 127) << 8;       // 256 spatial positions per block
    const int j   = idx[(long)b * SPATIAL + s0 + tid];
    const float4v* ep = (const float4v*)(emb + j * EDIM);
    float* obase = out + 1 + ((long)b << 21) + s0 + tid;
    #pragma unroll
    for (int cq = 0; cq < 16; ++cq) {
        float4v ev = ep[cq];                // emb[j][4cq..4cq+3], 16B L2 gather
        #pragma unroll
        for (int k = 0; k < 4; ++k)
            __builtin_nontemporal_store(ev[k], obase + ((long)(cq * 4 + k) << 15));
    }
}

// ---------------- final: scalars -------------------------------------------
__global__ void vq_final(const unsigned* __restrict__ counts,
                         const float* __restrict__ xpart,
                         const float* __restrict__ dpart,
                         float* __restrict__ out) {
    __shared__ float red[NCODES];
    int t = threadIdx.x;                   // 512 threads
    // entropy reduction
    float p = (float)counts[t] * (1.0f / 262144.0f);
    red[t] = p * logf(p + 1e-10f);
    __syncthreads();
    for (int m = 256; m; m >>= 1) {
        if (t < m) red[t] += red[t + m];
        __syncthreads();
    }
    float ppl = expf(-red[0]);
    __syncthreads();
    // loss reduction: 1024 xpart + 4096 dpart
    float s = xpart[t] + xpart[t + 512];
    #pragma unroll
    for (int i = 0; i < 8; ++i) s += dpart[t + 512 * i];
    red[t] = s;
    __syncthreads();
    for (int m = 256; m; m >>= 1) {
        if (t < m) red[t] += red[t + m];
        __syncthreads();
    }
    if (t == 0) {
        out[0]             = 1.25f * red[0] * (1.0f / 16777216.0f);
        out[1 + OUT_ELEMS] = ppl;
    }
}

extern "C" void kernel_launch(void* const* d_in, const int* in_sizes, int n_in,
                              void* d_out, int out_size, void* d_ws, size_t ws_size,
                              hipStream_t stream) {
    const float* x   = (const float*)d_in[0];
    const float* emb = (const float*)d_in[1];
    float* out = (float*)d_out;

    char* ws = (char*)d_ws;
    unsigned*       counts = (unsigned*)(ws + 64);          // 2 KB
    float*          eNormB = (float*)(ws + 4096);           // 2 KB
    short*          ebf    = (short*)(ws + 8192);           // 64 KB bf16(-2e)
    unsigned short* idx    = (unsigned short*)(ws + 73728); // 512 KB indices
    float*          xpart  = (float*)(ws + 598016);         // 4 KB (1024)
    float*          dpart  = (float*)(ws + 602112);         // 16 KB (4096)

    // xbf (32 MB, bf16 row-major [262144][64]) lives in the out buffer's
    // quantized region (64 MB), which vq_scatter fully overwrites afterwards.
    unsigned short* xbf = (unsigned short*)(out + 4);       // 16B-aligned

    vq_prep   <<<NCODES, 64, 0, stream>>>(emb, counts, eNormB, ebf);
    vq_xprep  <<<1024, 256, 0, stream>>>(x, xbf, xpart);
    vq_argmin <<<4096, 256, 0, stream>>>(xbf, eNormB, ebf, idx, dpart);
    vq_hist   <<<64, 256, 0, stream>>>(idx, counts);
    vq_scatter<<<1024, 256, 0, stream>>>(emb, idx, out);
    vq_final  <<<1, 512, 0, stream>>>(counts, xpart, dpart, out);
}

// Round 9
// 100.647 us; speedup vs baseline: 1.1229x; 1.1229x over previous
//
#include <hip/hip_runtime.h>
#include <hip/hip_bf16.h>
#include <float.h>

// VQ-VAE quantization for x:[8,64,32,32,32] f32, embedding:[512,64] f32.
// Outputs (flat, f32): [0] loss, [1..16777216] quantized [B,C,D,H,W], [16777217] perplexity.

#define EDIM      64
#define NCODES    512
#define SPATIAL   32768        // 32*32*32
#define OUT_ELEMS 16777216     // 8*64*32768
#define NROWS     262144       // 8*32768

typedef __attribute__((ext_vector_type(8))) short  short8;
typedef __attribute__((ext_vector_type(4))) float  float4v;
typedef __attribute__((ext_vector_type(4))) int    int4v;
typedef __attribute__((ext_vector_type(4))) unsigned short ushort4v;

static __device__ __forceinline__ unsigned pack_bf16x2(float lo, float hi) {
    union { float f; unsigned u; } a, b; a.f = lo; b.f = hi;
    unsigned ra = (a.u + 0x7FFFu + ((a.u >> 16) & 1u)) >> 16;   // RNE
    unsigned rb = (b.u + 0x7FFFu + ((b.u >> 16) & 1u)) & 0xFFFF0000u;
    return ra | rb;
}

// ---------------- prep: bf16(-2*e) table, |e|^2 + 0.5 key bias, zero counts -
__global__ void vq_prep(const float* __restrict__ emb,
                        unsigned* __restrict__ counts,
                        float* __restrict__ eNormB,
                        short* __restrict__ ebf) {
    int j = blockIdx.x;        // 512 blocks
    int c = threadIdx.x;       // 64 threads = 1 wave
    float v = emb[j * EDIM + c];
    union { float f; unsigned u; } t; t.f = -2.0f * v;
    ebf[j * EDIM + c] = (short)((t.u + 0x7FFFu + ((t.u >> 16) & 1u)) >> 16);
    float sq = v * v;
    #pragma unroll
    for (int m = 32; m; m >>= 1) sq += __shfl_xor(sq, m, 64);
    if (c == 0) {
        eNormB[j] = sq + 0.5f;   // key = 0.5 + |e|^2 - 2x.e  (positive, ~0.5)
        counts[j] = 0u;
    }
}

// ---------------- xprep: x[C][S] -> row-major bf16 xbf[row][64]; sum x^2 ----
__global__ __launch_bounds__(256) void vq_xprep(const float* __restrict__ x,
                                                unsigned short* __restrict__ xbf,
                                                float* __restrict__ xpart) {
    __shared__ float red4[4];
    const int tid = threadIdx.x;
    const int blk = blockIdx.x;           // 1024 blocks
    const int b   = blk >> 7;
    const int s0  = (blk & 127) << 8;     // 256 rows per block, 1 per thread
    const float* xp = x + ((long)b << 21) + s0 + tid;

    unsigned row[32];                     // this thread's row, packed bf16 pairs
    float x2 = 0.0f;
    #pragma unroll
    for (int c = 0; c < 64; c += 2) {
        float v0 = xp[(long)c << 15];         // coalesced: lanes contiguous in s
        float v1 = xp[(long)(c + 1) << 15];
        x2 += v0 * v0 + v1 * v1;
        row[c >> 1] = pack_bf16x2(v0, v1);
    }
    int4v* dst = (int4v*)(xbf + ((long)(b * SPATIAL + s0 + tid) << 6));
    #pragma unroll
    for (int q = 0; q < 8; ++q) dst[q] = *(int4v*)&row[q * 4];

    #pragma unroll
    for (int m = 32; m; m >>= 1) x2 += __shfl_xor(x2, m, 64);
    if ((tid & 63) == 0) red4[tid >> 6] = x2;
    __syncthreads();
    if (tid == 0) xpart[blk] = red4[0] + red4[1] + red4[2] + red4[3];
}

// ---------------- argmin: R7 shape + explicit B-prefetch pipeline -----------
// R7's VGPR=48 build issues B-loads right before use: 32 exposed ~200cy
// latencies per wave with every pipe idle. Prefetch jt+1's fragments during
// jt's MFMA chain; full unroll keeps all addresses immediate.
__global__ __launch_bounds__(256) void vq_argmin(
        const unsigned short* __restrict__ xbf,
        const float* __restrict__ eNormB,
        const short* __restrict__ ebf,
        unsigned short* __restrict__ idx_out,
        float* __restrict__ dpart) {

    __shared__ float red4[4];
    const int tid  = threadIdx.x;              // 256 threads = 4 waves
    const int wave = tid >> 6;
    const int lane = tid & 63;
    const int lrow = lane & 15;    // A-row / B-col / D-col lane field
    const int lk   = lane >> 4;    // k-chunk / D-row-group lane field
    const int row0 = blockIdx.x * 256 + wave * 64;   // 1024 blocks, 64 rows/wave

    // ---- A fragments: 4 row-tiles x 2 k-chunks, one dwordx4 each -----------
    short8 afr[4][2];
    #pragma unroll
    for (int r = 0; r < 4; ++r) {
        const long rbase = (long)(row0 + r * 16 + lrow) << 6;
        afr[r][0] = *(const short8*)(xbf + rbase + lk * 8);
        afr[r][1] = *(const short8*)(xbf + rbase + 32 + lk * 8);
    }

    // ---- scan 512 codes; key = float_bits(0.5 + |e|^2 - 2x.e) low9 <- j ----
    unsigned key[4][4];
    #pragma unroll
    for (int r = 0; r < 4; ++r)
        #pragma unroll
        for (int q = 0; q < 4; ++q) key[r][q] = 0xFFFFFFFFu;

    const short8* ebv = (const short8*)ebf;

    // prefetch jt=0
    short8 b0 = ebv[lrow * 8 + lk];
    short8 b1 = ebv[lrow * 8 + 4 + lk];
    float  en = eNormB[lrow];

    #pragma unroll
    for (int jt = 0; jt < 32; ++jt) {
        const int j = jt * 16 + lrow;          // this lane's code (B col)
        short8 c0 = b0; short8 c1 = b1; float ce = en;
        if (jt < 31) {                         // issue next-iter loads NOW
            const int jn = j + 16;
            b0 = ebv[jn * 8 + lk];
            b1 = ebv[jn * 8 + 4 + lk];
            en = eNormB[jn];
        }
        float4v cinit = {ce, ce, ce, ce};
        #pragma unroll
        for (int r = 0; r < 4; ++r) {
            float4v acc = cinit;
            acc = __builtin_amdgcn_mfma_f32_16x16x32_bf16(afr[r][0], c0, acc, 0, 0, 0);
            acc = __builtin_amdgcn_mfma_f32_16x16x32_bf16(afr[r][1], c1, acc, 0, 0, 0);
            #pragma unroll
            for (int q = 0; q < 4; ++q) {
                unsigned u = (__float_as_uint(acc[q]) & 0xFFFFFE00u) | (unsigned)j;
                key[r][q] = min(key[r][q], u);
            }
        }
    }

    // ---- min butterfly across the 16 code-lanes ----------------------------
    #pragma unroll
    for (int r = 0; r < 4; ++r)
        #pragma unroll
        for (int q = 0; q < 4; ++q) {
            unsigned k = key[r][q];
            #pragma unroll
            for (int m = 1; m < 16; m <<= 1)
                k = min(k, (unsigned)__shfl_xor((int)k, m, 64));
            key[r][q] = k;
        }

    // ---- lrow==0 lanes own 16 rows: write idx, sum (d_min) -----------------
    float smin = 0.0f;
    if (lrow == 0) {
        #pragma unroll
        for (int r = 0; r < 4; ++r) {
            ushort4v iv;
            #pragma unroll
            for (int q = 0; q < 4; ++q) {
                iv[q] = (unsigned short)(key[r][q] & 511u);
                smin += __uint_as_float(key[r][q] & 0xFFFFFE00u) - 0.5f;
            }
            *(ushort4v*)&idx_out[row0 + r * 16 + lk * 4] = iv;
        }
    }
    #pragma unroll
    for (int m = 32; m; m >>= 1) smin += __shfl_xor(smin, m, 64);
    if (lane == 0) red4[wave] = smin;
    __syncthreads();
    if (tid == 0) dpart[blockIdx.x] = red4[0] + red4[1] + red4[2] + red4[3];
}

// ---------------- histogram: LDS bins, few global atomics -------------------
__global__ __launch_bounds__(256) void vq_hist(const unsigned short* __restrict__ idx,
                                               unsigned* __restrict__ counts) {
    __shared__ unsigned h[NCODES];
    const int tid = threadIdx.x;
    h[tid] = 0u; h[tid + 256] = 0u;
    __syncthreads();
    const unsigned* p = (const unsigned*)idx;          // 2 ushorts per load
    for (int i = blockIdx.x * 256 + tid; i < NROWS / 2; i += 64 * 256) {
        unsigned v = p[i];
        atomicAdd(&h[v & 0xFFFFu], 1u);
        atomicAdd(&h[v >> 16], 1u);
    }
    __syncthreads();
    atomicAdd(&counts[tid], h[tid]);
    atomicAdd(&counts[tid + 256], h[tid + 256]);
}

// ---------------- scatter: exact f32 codebook rows -> [C][S] output ---------
__global__ __launch_bounds__(256) void vq_scatter(const float* __restrict__ emb,
                                                  const unsigned short* __restrict__ idx,
                                                  float* __restrict__ out) {
    const int tid = threadIdx.x;
    const int blk = blockIdx.x;             // 1024 blocks
    const int b   = blk >> 7;
    const int s0  = (blk & 127) << 8;       // 256 spatial positions per block
    const int j   = idx[(long)b * SPATIAL + s0 + tid];
    const float4v* ep = (const float4v*)(emb + j * EDIM);
    float* obase = out + 1 + ((long)b << 21) + s0 + tid;
    #pragma unroll
    for (int cq = 0; cq < 16; ++cq) {
        float4v ev = ep[cq];                // emb[j][4cq..4cq+3], 16B L2 gather
        #pragma unroll
        for (int k = 0; k < 4; ++k)
            __builtin_nontemporal_store(ev[k], obase + ((long)(cq * 4 + k) << 15));
    }
}

// ---------------- final: scalars -------------------------------------------
__global__ void vq_final(const unsigned* __restrict__ counts,
                         const float* __restrict__ xpart,
                         const float* __restrict__ dpart,
                         float* __restrict__ out) {
    __shared__ float red[NCODES];
    int t = threadIdx.x;                   // 512 threads
    // entropy reduction
    float p = (float)counts[t] * (1.0f / 262144.0f);
    red[t] = p * logf(p + 1e-10f);
    __syncthreads();
    for (int m = 256; m; m >>= 1) {
        if (t < m) red[t] += red[t + m];
        __syncthreads();
    }
    float ppl = expf(-red[0]);
    __syncthreads();
    // loss reduction: sum 1024 xpart + 1024 dpart
    red[t] = xpart[t] + xpart[t + 512] + dpart[t] + dpart[t + 512];
    __syncthreads();
    for (int m = 256; m; m >>= 1) {
        if (t < m) red[t] += red[t + m];
        __syncthreads();
    }
    if (t == 0) {
        out[0]             = 1.25f * red[0] * (1.0f / 16777216.0f);
        out[1 + OUT_ELEMS] = ppl;
    }
}

extern "C" void kernel_launch(void* const* d_in, const int* in_sizes, int n_in,
                              void* d_out, int out_size, void* d_ws, size_t ws_size,
                              hipStream_t stream) {
    const float* x   = (const float*)d_in[0];
    const float* emb = (const float*)d_in[1];
    float* out = (float*)d_out;

    char* ws = (char*)d_ws;
    unsigned*       counts = (unsigned*)(ws + 64);          // 2 KB
    float*          eNormB = (float*)(ws + 4096);           // 2 KB
    short*          ebf    = (short*)(ws + 8192);           // 64 KB bf16(-2e)
    unsigned short* idx    = (unsigned short*)(ws + 73728); // 512 KB indices
    float*          xpart  = (float*)(ws + 598016);         // 4 KB (1024)
    float*          dpart  = (float*)(ws + 602112);         // 4 KB (1024)

    // xbf (32 MB, bf16 row-major [262144][64]) lives in the out buffer's
    // quantized region (64 MB), which vq_scatter fully overwrites afterwards.
    unsigned short* xbf = (unsigned short*)(out + 4);       // 16B-aligned

    vq_prep   <<<NCODES, 64, 0, stream>>>(emb, counts, eNormB, ebf);
    vq_xprep  <<<1024, 256, 0, stream>>>(x, xbf, xpart);
    vq_argmin <<<1024, 256, 0, stream>>>(xbf, eNormB, ebf, idx, dpart);
    vq_hist   <<<64, 256, 0, stream>>>(idx, counts);
    vq_scatter<<<1024, 256, 0, stream>>>(emb, idx, out);
    vq_final  <<<1, 512, 0, stream>>>(counts, xpart, dpart, out);
}

// Round 10
// 82.964 us; speedup vs baseline: 1.3622x; 1.2131x over previous
//
#include <hip/hip_runtime.h>
#include <hip/hip_bf16.h>
#include <float.h>

// VQ-VAE quantization for x:[8,64,32,32,32] f32, embedding:[512,64] f32.
// Outputs (flat, f32): [0] loss, [1..16777216] quantized [B,C,D,H,W], [16777217] perplexity.

#define EDIM      64
#define NCODES    512
#define SPATIAL   32768        // 32*32*32
#define OUT_ELEMS 16777216     // 8*64*32768
#define NROWS     262144       // 8*32768

typedef __attribute__((ext_vector_type(8))) short  short8;
typedef __attribute__((ext_vector_type(4))) float  float4v;
typedef __attribute__((ext_vector_type(4))) int    int4v;
typedef __attribute__((ext_vector_type(4))) unsigned short ushort4v;

static __device__ __forceinline__ unsigned pack_bf16x2(float lo, float hi) {
    union { float f; unsigned u; } a, b; a.f = lo; b.f = hi;
    unsigned ra = (a.u + 0x7FFFu + ((a.u >> 16) & 1u)) >> 16;   // RNE
    unsigned rb = (b.u + 0x7FFFu + ((b.u >> 16) & 1u)) & 0xFFFF0000u;
    return ra | rb;
}

// ---------------- prep: bf16(-2*e) table, |e|^2 + 0.5 key bias, zero counts -
__global__ void vq_prep(const float* __restrict__ emb,
                        unsigned* __restrict__ counts,
                        float* __restrict__ eNormB,
                        short* __restrict__ ebf) {
    int j = blockIdx.x;        // 512 blocks
    int c = threadIdx.x;       // 64 threads = 1 wave
    float v = emb[j * EDIM + c];
    union { float f; unsigned u; } t; t.f = -2.0f * v;
    ebf[j * EDIM + c] = (short)((t.u + 0x7FFFu + ((t.u >> 16) & 1u)) >> 16);
    float sq = v * v;
    #pragma unroll
    for (int m = 32; m; m >>= 1) sq += __shfl_xor(sq, m, 64);
    if (c == 0) {
        eNormB[j] = sq + 0.5f;   // key = 0.5 + |e|^2 - 2x.e  (positive, ~0.5)
        counts[j] = 0u;
    }
}

// ---------------- fused: load+transpose -> argmin -> scatter ----------------
// Per block (256 thr, 1024 blocks): 256 rows.
//  P1: coalesced f32 x-read (xprep's pattern), bf16-pack, XOR-swizzled LDS
//      store; exact f32 sum(x^2).
//  P2: A-frags from LDS; R7's MFMA scan of the global bf16(-2e) table;
//      packed-key min + butterfly; idx -> LDS + global (for hist).
//  P3: in-block scatter: gather emb rows (L2), nontemporal [C][S] stores.
// Phases overlap ACROSS the ~4 resident blocks/CU.
__global__ __launch_bounds__(256) void vq_fused(
        const float* __restrict__ x,
        const float* __restrict__ emb,
        const float* __restrict__ eNormB,
        const short* __restrict__ ebf,
        unsigned short* __restrict__ idx_out,
        float* __restrict__ out,
        float* __restrict__ xpart,
        float* __restrict__ dpart) {

    __shared__ short          xs[256 * 64];     // 32 KB, XOR-swizzled rows
    __shared__ unsigned short idx_lds[256];
    __shared__ float          red8[8];

    const int tid  = threadIdx.x;               // 256 threads = 4 waves
    const int wave = tid >> 6;
    const int lane = tid & 63;
    const int lrow = lane & 15;    // A-row / B-col / D-col lane field
    const int lk   = lane >> 4;    // k-chunk / D-row-group lane field
    const int blk  = blockIdx.x;   // 1024 blocks
    const int b    = blk >> 7;
    const int s0   = (blk & 127) << 8;          // 256 rows per block
    const long obase = ((long)b << 21) + s0 + tid;
    const float* xp = x + obase;

    // ---- P1: row tid, coalesced channel loads, swizzled LDS write ----------
    // LDS byte = row*128 + (chunk*16 ^ ((row&7)<<4)), same XOR on read side.
    float x2 = 0.0f;
    const int wswz = (tid & 7) << 4;
    #pragma unroll
    for (int co = 0; co < 8; ++co) {
        unsigned d[4];
        #pragma unroll
        for (int i = 0; i < 4; ++i) {
            float v0 = xp[(long)(co * 8 + 2 * i)     << 15];
            float v1 = xp[(long)(co * 8 + 2 * i + 1) << 15];
            x2 += v0 * v0 + v1 * v1;
            d[i] = pack_bf16x2(v0, v1);
        }
        *(int4v*)((char*)xs + tid * 128 + ((co * 16) ^ wswz)) = *(int4v*)d;
    }
    __syncthreads();

    // ---- P2a: A fragments from LDS (rows 8-stripe covers all 32 banks) -----
    short8 afr[4][2];
    const int swz = (lrow & 7) << 4;
    #pragma unroll
    for (int r = 0; r < 4; ++r) {
        const int row = wave * 64 + r * 16 + lrow;
        afr[r][0] = *(const short8*)((char*)xs + row * 128 + ((lk * 16)      ^ swz));
        afr[r][1] = *(const short8*)((char*)xs + row * 128 + ((64 + lk * 16) ^ swz));
    }

    // ---- P2b: scan 512 codes; key = bits(0.5 + |e|^2 - 2x.e) low9 <- j -----
    unsigned key[4][4];
    #pragma unroll
    for (int r = 0; r < 4; ++r)
        #pragma unroll
        for (int q = 0; q < 4; ++q) key[r][q] = 0xFFFFFFFFu;

    const short8* ebv = (const short8*)ebf;
    #pragma unroll
    for (int jt = 0; jt < 32; ++jt) {
        const int j = jt * 16 + lrow;                 // this lane's code (B col)
        short8 b0 = ebv[j * 8 + lk];                  // channels [lk*8 .. +7]
        short8 b1 = ebv[j * 8 + 4 + lk];              // channels [32+lk*8 .. +7]
        float  en = eNormB[j];
        float4v cinit = {en, en, en, en};
        #pragma unroll
        for (int r = 0; r < 4; ++r) {
            float4v acc = cinit;
            acc = __builtin_amdgcn_mfma_f32_16x16x32_bf16(afr[r][0], b0, acc, 0, 0, 0);
            acc = __builtin_amdgcn_mfma_f32_16x16x32_bf16(afr[r][1], b1, acc, 0, 0, 0);
            #pragma unroll
            for (int q = 0; q < 4; ++q) {
                unsigned u = (__float_as_uint(acc[q]) & 0xFFFFFE00u) | (unsigned)j;
                key[r][q] = min(key[r][q], u);
            }
        }
    }

    // ---- P2c: min butterfly across the 16 code-lanes -----------------------
    #pragma unroll
    for (int r = 0; r < 4; ++r)
        #pragma unroll
        for (int q = 0; q < 4; ++q) {
            unsigned k = key[r][q];
            #pragma unroll
            for (int m = 1; m < 16; m <<= 1)
                k = min(k, (unsigned)__shfl_xor((int)k, m, 64));
            key[r][q] = k;
        }

    // ---- P2d: lrow==0 lanes own 16 rows: idx -> LDS + global, d_min sum ----
    float smin = 0.0f;
    if (lrow == 0) {
        #pragma unroll
        for (int r = 0; r < 4; ++r) {
            ushort4v iv;
            #pragma unroll
            for (int q = 0; q < 4; ++q) {
                iv[q] = (unsigned short)(key[r][q] & 511u);
                smin += __uint_as_float(key[r][q] & 0xFFFFFE00u) - 0.5f;
            }
            const int rr = wave * 64 + r * 16 + lk * 4;
            *(ushort4v*)&idx_lds[rr] = iv;
            *(ushort4v*)&idx_out[(long)b * SPATIAL + s0 + rr] = iv;
        }
    }
    // per-wave partials: x2 (all lanes) and smin (lrow==0 lanes)
    float tot = x2;
    #pragma unroll
    for (int m = 32; m; m >>= 1) tot += __shfl_xor(tot, m, 64);
    #pragma unroll
    for (int m = 32; m; m >>= 1) smin += __shfl_xor(smin, m, 64);
    if (lane == 0) { red8[wave] = tot; red8[wave + 4] = smin; }
    __syncthreads();
    if (tid == 0) {
        xpart[blk] = red8[0] + red8[1] + red8[2] + red8[3];
        dpart[blk] = red8[4] + red8[5] + red8[6] + red8[7];
    }

    // ---- P3: scatter: gather emb row (L2), nontemporal [C][S] stores -------
    const int jj = idx_lds[tid];
    const float4v* ep = (const float4v*)(emb + jj * EDIM);
    float* op = out + 1 + obase;
    #pragma unroll
    for (int cq = 0; cq < 16; ++cq) {
        float4v ev = ep[cq];                // emb[jj][4cq..4cq+3]
        #pragma unroll
        for (int k = 0; k < 4; ++k)
            __builtin_nontemporal_store(ev[k], op + ((long)(cq * 4 + k) << 15));
    }
}

// ---------------- histogram: LDS bins, few global atomics -------------------
__global__ __launch_bounds__(256) void vq_hist(const unsigned short* __restrict__ idx,
                                               unsigned* __restrict__ counts) {
    __shared__ unsigned h[NCODES];
    const int tid = threadIdx.x;
    h[tid] = 0u; h[tid + 256] = 0u;
    __syncthreads();
    const unsigned* p = (const unsigned*)idx;          // 2 ushorts per load
    for (int i = blockIdx.x * 256 + tid; i < NROWS / 2; i += 64 * 256) {
        unsigned v = p[i];
        atomicAdd(&h[v & 0xFFFFu], 1u);
        atomicAdd(&h[v >> 16], 1u);
    }
    __syncthreads();
    atomicAdd(&counts[tid], h[tid]);
    atomicAdd(&counts[tid + 256], h[tid + 256]);
}

// ---------------- final: scalars -------------------------------------------
__global__ void vq_final(const unsigned* __restrict__ counts,
                         const float* __restrict__ xpart,
                         const float* __restrict__ dpart,
                         float* __restrict__ out) {
    __shared__ float red[NCODES];
    int t = threadIdx.x;                   // 512 threads
    // entropy reduction
    float p = (float)counts[t] * (1.0f / 262144.0f);
    red[t] = p * logf(p + 1e-10f);
    __syncthreads();
    for (int m = 256; m; m >>= 1) {
        if (t < m) red[t] += red[t + m];
        __syncthreads();
    }
    float ppl = expf(-red[0]);
    __syncthreads();
    // loss reduction: sum 1024 xpart + 1024 dpart
    red[t] = xpart[t] + xpart[t + 512] + dpart[t] + dpart[t + 512];
    __syncthreads();
    for (int m = 256; m; m >>= 1) {
        if (t < m) red[t] += red[t + m];
        __syncthreads();
    }
    if (t == 0) {
        out[0]             = 1.25f * red[0] * (1.0f / 16777216.0f);
        out[1 + OUT_ELEMS] = ppl;
    }
}

extern "C" void kernel_launch(void* const* d_in, const int* in_sizes, int n_in,
                              void* d_out, int out_size, void* d_ws, size_t ws_size,
                              hipStream_t stream) {
    const float* x   = (const float*)d_in[0];
    const float* emb = (const float*)d_in[1];
    float* out = (float*)d_out;

    char* ws = (char*)d_ws;
    unsigned*       counts = (unsigned*)(ws + 64);          // 2 KB
    float*          eNormB = (float*)(ws + 4096);           // 2 KB
    short*          ebf    = (short*)(ws + 8192);           // 64 KB bf16(-2e)
    unsigned short* idx    = (unsigned short*)(ws + 73728); // 512 KB indices
    float*          xpart  = (float*)(ws + 598016);         // 4 KB (1024)
    float*          dpart  = (float*)(ws + 602112);         // 4 KB (1024)

    vq_prep <<<NCODES, 64, 0, stream>>>(emb, counts, eNormB, ebf);
    vq_fused<<<1024, 256, 0, stream>>>(x, emb, eNormB, ebf, idx, out, xpart, dpart);
    vq_hist <<<64, 256, 0, stream>>>(idx, counts);
    vq_final<<<1, 512, 0, stream>>>(counts, xpart, dpart, out);
}